// Round 11
// baseline (452.081 us; speedup 1.0000x reference)
//
#include <hip/hip_runtime.h>

#define N_NODES 50000
#define N_EDGES 800000
#define DIM 128
#define NGROUPS 64
#define NCLS 32
#define BN_EPS 1e-5f
#define SCAN_BLOCKS 98  // ceil(50000/512)
#define CPY 50048       // padded per-copy stride

// prep grid layout
#define PREP_COUNT 3125
#define PREP_GSTART (PREP_COUNT + 196)   // 3321
#define PREP_CONVX (PREP_GSTART + 2048)  // 5369
#define PREP_W6 (PREP_CONVX + 384)       // 5753
#define PREP_TOTAL (PREP_W6 + 192)       // 5945

typedef short short8_t __attribute__((ext_vector_type(8)));
typedef float f32x4 __attribute__((ext_vector_type(4)));
typedef const __attribute__((address_space(1))) unsigned char* gptr_t;
typedef __attribute__((address_space(3))) unsigned char* sptr_t;

__device__ __forceinline__ unsigned short f2bf(float f) {
    unsigned int u = __float_as_uint(f);
    u += 0x7FFFu + ((u >> 16) & 1u);   // round-to-nearest-even
    return (unsigned short)(u >> 16);
}
__device__ __forceinline__ float bf_lo(unsigned int u) { return __uint_as_float(u << 16); }
__device__ __forceinline__ float bf_hi(unsigned int u) { return __uint_as_float(u & 0xffff0000u); }

// ---------------- fused prep: count (8 privatized copies, emits pos_e) + gstart + converts ----

__global__ __launch_bounds__(256) void prep_kernel(
    const int* __restrict__ ei, int* __restrict__ cnt8, int* __restrict__ pos_e,
    const int* __restrict__ batch, int* __restrict__ g_start,
    const float* __restrict__ x, unsigned int* __restrict__ X0,
    const float* w0, const float* w1, const float* w2,
    const float* w3, const float* w4, const float* w5,
    unsigned short* __restrict__ Wb,
    const float* __restrict__ Wjk, unsigned short* __restrict__ Wjkb) {
    int b = blockIdx.x, t = threadIdx.x;
    if (b < PREP_COUNT) {
        int e = b * 256 + t;   // 3125*256 == 800000 exactly
        int dst = ei[N_EDGES + e];
        pos_e[e] = atomicAdd(&cnt8[(b & 7) * CPY + dst], 1);
    } else if (b < PREP_GSTART) {
        int i = (b - PREP_COUNT) * 256 + t;
        if (i < N_NODES) {
            int bb = batch[i];
            if (i == 0) {
                for (int g = 0; g <= bb; ++g) g_start[g] = 0;
            } else {
                int p = batch[i - 1];
                for (int g = p + 1; g <= bb; ++g) g_start[g] = i;
            }
            if (i == N_NODES - 1) {
                for (int g = bb + 1; g <= NGROUPS; ++g) g_start[g] = N_NODES;
            }
        }
    } else if (b < PREP_CONVX) {
        const float4* s4 = (const float4*)x;
        const int total4 = N_NODES * 32;
        for (int idx = (b - PREP_GSTART) * 256 + t; idx < total4; idx += 2048 * 256) {
            float4 v = s4[idx];
            X0[idx * 2] = (unsigned int)f2bf(v.x) | ((unsigned int)f2bf(v.y) << 16);
            X0[idx * 2 + 1] = (unsigned int)f2bf(v.z) | ((unsigned int)f2bf(v.w) << 16);
        }
    } else if (b < PREP_W6) {
        int idx = (b - PREP_CONVX) * 256 + t;   // 0 .. 6*16384
        int mat = idx >> 14, off = idx & 16383;
        const float* s = (mat == 0) ? w0 : (mat == 1) ? w1 : (mat == 2) ? w2
                       : (mat == 3) ? w3 : (mat == 4) ? w4 : w5;
        Wb[idx] = f2bf(s[off]);
    } else {
        int idx = (b - PREP_W6) * 256 + t;   // 0 .. 49152
        int d = idx / 384, k = idx - d * 384;
        int part = k >> 7, kk = k & 127;
        Wjkb[part * 16384 + d * 128 + kk] = f2bf(Wjk[idx]);
    }
}

// ---------------- decoupled-lookback scan over 8 copies; emits per-copy sub-offsets ----------------

#define FLG_AGG 0x40000000u
#define FLG_PFX 0x80000000u
#define FLG_VAL 0x3FFFFFFFu

__global__ __launch_bounds__(256) void scan_kernel(const int* __restrict__ cnt8,
                                                   int* __restrict__ row_start,
                                                   int* __restrict__ start8,
                                                   unsigned int* __restrict__ status) {
    int b = blockIdx.x, t = threadIdx.x;
    int idx = b * 512 + 2 * t;
    int c0[8], c1[8];
    int v0 = 0, v1 = 0;
    if (idx + 1 < N_NODES) {
        #pragma unroll
        for (int q = 0; q < 8; ++q) {
            int2 p = ((const int2*)(cnt8 + q * CPY))[b * 256 + t];
            c0[q] = p.x; c1[q] = p.y;
            v0 += p.x; v1 += p.y;
        }
    } else if (idx < N_NODES) {
        #pragma unroll
        for (int q = 0; q < 8; ++q) {
            c0[q] = cnt8[q * CPY + idx]; c1[q] = 0;
            v0 += c0[q];
        }
    } else {
        #pragma unroll
        for (int q = 0; q < 8; ++q) { c0[q] = 0; c1[q] = 0; }
    }
    int pair = v0 + v1;
    int lane = t & 63, w = t >> 6;
    int x = pair;
    #pragma unroll
    for (int off = 1; off < 64; off <<= 1) {
        int t2 = __shfl_up(x, off);
        if (lane >= off) x += t2;
    }
    __shared__ int wtot[4], wexcl[4];
    __shared__ int s_tot;
    __shared__ unsigned int s_run;
    if (lane == 63) wtot[w] = x;
    __syncthreads();
    if (t == 0) {
        int c = 0;
        #pragma unroll
        for (int i = 0; i < 4; ++i) { wexcl[i] = c; c += wtot[i]; }
        s_tot = c;
        unsigned int pub = (b == 0) ? (FLG_PFX | (unsigned int)c) : (FLG_AGG | (unsigned int)c);
        atomicExch(&status[b], pub);
    }
    __syncthreads();
    int total = s_tot;
    if (t == 0) {
        unsigned int run = 0;
        if (b > 0) {
            int i = b - 1;
            while (true) {
                unsigned int s = atomicAdd(&status[i], 0u);
                if (s & FLG_PFX) { run += s & FLG_VAL; break; }
                if (s & FLG_AGG) { run += s & FLG_VAL; --i; }
            }
            atomicExch(&status[b], FLG_PFX | (run + (unsigned int)total));
        }
        s_run = run;
    }
    __syncthreads();
    int gexcl = (int)s_run + wexcl[w] + (x - pair);
    if (idx < N_NODES) {
        row_start[idx] = gexcl;
        int run = gexcl;
        #pragma unroll
        for (int q = 0; q < 8; ++q) { start8[q * CPY + idx] = run; run += c0[q]; }
    }
    if (idx + 1 < N_NODES) {
        int g1 = gexcl + v0;
        row_start[idx + 1] = g1;
        int run = g1;
        #pragma unroll
        for (int q = 0; q < 8; ++q) { start8[q * CPY + idx + 1] = run; run += c1[q]; }
    }
    if (b == 0 && t == 0) row_start[N_NODES] = N_EDGES;
}

// ---------------- fill: atomic-free (positions precomputed in prep) ----------------

__global__ __launch_bounds__(256) void fill_kernel(const int* __restrict__ ei,
                                                   const int* __restrict__ pos_e,
                                                   const int* __restrict__ start8,
                                                   int* __restrict__ csr) {
    int b = blockIdx.x;   // 3125
    int e = b * 256 + threadIdx.x;
    int dst = ei[N_EDGES + e];
    csr[start8[(b & 7) * CPY + dst] + pos_e[e]] = ei[e];
}

// ---------------- mean aggregation: 16 lanes/row x 4 edges x 4-deep ILP (proven best) ------

#define ACC8(u)                                                                           \
    do {                                                                                  \
        a[0] += bf_lo((u).x); a[1] += bf_hi((u).x);                                        \
        a[2] += bf_lo((u).y); a[3] += bf_hi((u).y);                                        \
        a[4] += bf_lo((u).z); a[5] += bf_hi((u).z);                                        \
        a[6] += bf_lo((u).w); a[7] += bf_hi((u).w);                                        \
    } while (0)

__global__ __launch_bounds__(256) void agg_kernel(const unsigned short* __restrict__ xin,
                                                  const int* __restrict__ csr,
                                                  const int* __restrict__ row_start,
                                                  unsigned short* __restrict__ out) {
    int node = blockIdx.x * 4 + (threadIdx.x >> 6);
    int lane = threadIdx.x & 63;
    int g = lane >> 4, s16 = lane & 15;
    const uint4* base = (const uint4*)xin;   // one row = 16 uint4
    int cs = row_start[node], ce = row_start[node + 1];
    float a[8] = {0.f, 0.f, 0.f, 0.f, 0.f, 0.f, 0.f, 0.f};
    int i = cs;
    for (; i + 16 <= ce; i += 16) {
        int e0 = csr[i + g], e1 = csr[i + 4 + g], e2 = csr[i + 8 + g], e3 = csr[i + 12 + g];
        uint4 u0 = base[e0 * 16 + s16];
        uint4 u1 = base[e1 * 16 + s16];
        uint4 u2 = base[e2 * 16 + s16];
        uint4 u3 = base[e3 * 16 + s16];
        ACC8(u0); ACC8(u1); ACC8(u2); ACC8(u3);
    }
    if (i + 8 <= ce) {
        int e0 = csr[i + g], e1 = csr[i + 4 + g];
        uint4 u0 = base[e0 * 16 + s16];
        uint4 u1 = base[e1 * 16 + s16];
        ACC8(u0); ACC8(u1);
        i += 8;
    }
    if (i + 4 <= ce) {
        int e0 = csr[i + g];
        uint4 u0 = base[e0 * 16 + s16];
        ACC8(u0);
        i += 4;
    }
    if (i + g < ce) {
        int e0 = csr[i + g];
        uint4 u0 = base[e0 * 16 + s16];
        ACC8(u0);
    }
    #pragma unroll
    for (int k = 0; k < 8; ++k) {
        a[k] += __shfl_xor(a[k], 16);
        a[k] += __shfl_xor(a[k], 32);
    }
    if (g == 0) {
        int deg = ce - cs;
        float inv = 1.f / (float)(deg > 0 ? deg : 1);
        uint4 p;
        p.x = (unsigned int)f2bf(a[0] * inv) | ((unsigned int)f2bf(a[1] * inv) << 16);
        p.y = (unsigned int)f2bf(a[2] * inv) | ((unsigned int)f2bf(a[3] * inv) << 16);
        p.z = (unsigned int)f2bf(a[4] * inv) | ((unsigned int)f2bf(a[5] * inv) << 16);
        p.w = (unsigned int)f2bf(a[6] * inv) | ((unsigned int)f2bf(a[7] * inv) << 16);
        ((uint4*)out)[node * 16 + s16] = p;
    }
}

// ---------------- MFMA linear: C(bf16) = sum_p A_p @ W_p^T + bias [relu] ----------------
// STATS: shfl-reduced column sum/sumsq atomically accumulated into sums_out[256].
// BNFUSE: A_{P-1} is raw (pre-BN) — apply per-column affine+PReLU to its fragments,
//         coefs built in LDS from sums_in (exact fp32 stats) + gamma/beta/alpha.

template <int P, int ROWS, int RELU, int STATS, int BNFUSE>
__global__ __launch_bounds__(256, 2) void mfma_linear(
    const unsigned short* __restrict__ A0, const unsigned short* __restrict__ A1,
    const unsigned short* __restrict__ A2,
    const unsigned short* __restrict__ W0, const unsigned short* __restrict__ W1,
    const unsigned short* __restrict__ W2,
    const float* __restrict__ bias, unsigned short* __restrict__ C,
    float* __restrict__ sums_out,
    const float* __restrict__ sums_in, const float* __restrict__ bn_g,
    const float* __restrict__ bn_b, const float* __restrict__ bn_a,
    int n_rows) {
    constexpr int S = P * 16;          // 16B slots per LDS row
    constexpr int MR = ROWS / 32;      // m-frags per wave
    __shared__ char lds[ROWS * P * 256];
    __shared__ float csc[128], csf[128];
    int t = threadIdx.x;
    int lane = t & 63;
    int wr = (t >> 7) & 1, wc = (t >> 6) & 1;
    int row_base = blockIdx.x * ROWS;

    // stage activations: LDS linear dest, swizzled global source
    #pragma unroll
    for (int c = 0; c < (ROWS * S) / 256; ++c) {
        int flat = c * 256 + t;
        int row = flat / S;
        int s = flat - row * S;
        int ss = s ^ (row & 7);
        int grow = row_base + row;
        if (grow >= n_rows) grow = n_rows - 1;
        const unsigned short* Ap = (ss < 16) ? A0 : (ss < 32 ? A1 : A2);
        const unsigned short* srcp = Ap + (size_t)grow * 128 + (ss & 15) * 8;
        __builtin_amdgcn_global_load_lds((gptr_t)srcp, (sptr_t)(lds + flat * 16), 16, 0, 0);
    }

    float alpha = 0.f;
    if (BNFUSE) {
        if (t < 128) {
            float m = sums_in[t] * (1.f / N_NODES);
            float var = sums_in[128 + t] * (1.f / N_NODES) - m * m;
            float s = bn_g[t] * rsqrtf(var + BN_EPS);
            csc[t] = s;
            csf[t] = bn_b[t] - m * s;
        }
        alpha = bn_a[0];
    }

    const unsigned short* Wp[3] = {W0, W1, W2};
    short8_t bcur[4][4], bnxt[4][4];
    #pragma unroll
    for (int ksp = 0; ksp < 4; ++ksp)
        #pragma unroll
        for (int nn = 0; nn < 4; ++nn) {
            int col = wc * 64 + nn * 16 + (lane & 15);
            int k0 = ksp * 32 + (lane >> 4) * 8;
            bcur[ksp][nn] = *(const short8_t*)(W0 + col * 128 + k0);
        }

    f32x4 acc[MR][4];
    #pragma unroll
    for (int m = 0; m < MR; ++m)
        #pragma unroll
        for (int nn = 0; nn < 4; ++nn)
            acc[m][nn] = (f32x4){0.f, 0.f, 0.f, 0.f};

    __syncthreads();   // drains vmcnt (global_load_lds); csc/csf visible

    #pragma unroll
    for (int p = 0; p < P; ++p) {
        if (p + 1 < P) {
            #pragma unroll
            for (int ksp = 0; ksp < 4; ++ksp)
                #pragma unroll
                for (int nn = 0; nn < 4; ++nn) {
                    int col = wc * 64 + nn * 16 + (lane & 15);
                    int k0 = ksp * 32 + (lane >> 4) * 8;
                    bnxt[ksp][nn] = *(const short8_t*)(Wp[p + 1] + col * 128 + k0);
                }
        }
        #pragma unroll
        for (int ksp = 0; ksp < 4; ++ksp) {
            int ks = p * 4 + ksp;
            short8_t a[MR];
            #pragma unroll
            for (int m = 0; m < MR; ++m) {
                int row = wr * (ROWS / 2) + m * 16 + (lane & 15);
                int s = ks * 4 + (lane >> 4);
                int off = row * (P * 256) + ((s ^ (row & 7)) * 16);
                a[m] = *(const short8_t*)(lds + off);
            }
            if (BNFUSE && p == P - 1) {
                int c0 = ksp * 32 + (lane >> 4) * 8;   // local column in A_{P-1}
                #pragma unroll
                for (int m = 0; m < MR; ++m) {
                    unsigned int* au = (unsigned int*)&a[m];
                    #pragma unroll
                    for (int u = 0; u < 4; ++u) {
                        int c = c0 + u * 2;
                        float lo = bf_lo(au[u]) * csc[c] + csf[c];
                        float hi = bf_hi(au[u]) * csc[c + 1] + csf[c + 1];
                        lo = lo >= 0.f ? lo : alpha * lo;
                        hi = hi >= 0.f ? hi : alpha * hi;
                        au[u] = (unsigned int)f2bf(lo) | ((unsigned int)f2bf(hi) << 16);
                    }
                }
            }
            #pragma unroll
            for (int m = 0; m < MR; ++m)
                #pragma unroll
                for (int nn = 0; nn < 4; ++nn)
                    acc[m][nn] = __builtin_amdgcn_mfma_f32_16x16x32_bf16(a[m], bcur[ksp][nn], acc[m][nn], 0, 0, 0);
        }
        if (p + 1 < P) {
            #pragma unroll
            for (int ksp = 0; ksp < 4; ++ksp)
                #pragma unroll
                for (int nn = 0; nn < 4; ++nn)
                    bcur[ksp][nn] = bnxt[ksp][nn];
        }
    }

    // epilogue: bias [+relu], bf16 store (+ atomic BN stats from fp32)
    #pragma unroll
    for (int nn = 0; nn < 4; ++nn) {
        int col = wc * 64 + nn * 16 + (lane & 15);
        float badd = bias[col];
        float ps = 0.f, pq = 0.f;
        #pragma unroll
        for (int m = 0; m < MR; ++m) {
            #pragma unroll
            for (int j = 0; j < 4; ++j) {
                int row = row_base + wr * (ROWS / 2) + m * 16 + (lane >> 4) * 4 + j;
                if (row < n_rows) {
                    float v = acc[m][nn][j] + badd;
                    if (RELU) v = fmaxf(v, 0.f);
                    C[(size_t)row * 128 + col] = f2bf(v);
                    if (STATS) { ps += v; pq += v * v; }
                }
            }
        }
        if (STATS) {
            ps += __shfl_xor(ps, 16); ps += __shfl_xor(ps, 32);
            pq += __shfl_xor(pq, 16); pq += __shfl_xor(pq, 32);
            if (lane < 16) {
                atomicAdd(&sums_out[col], ps);
                atomicAdd(&sums_out[128 + col], pq);
            }
        }
    }
}

// ---------------- BN apply: coefs from sums in LDS; bf16 Y in, bf16 X out ----------------

__global__ __launch_bounds__(256) void bn_apply_kernel(
    const uint4* __restrict__ y4, const float* __restrict__ sums,
    const float* __restrict__ g, const float* __restrict__ b,
    const float* __restrict__ a, uint4* __restrict__ xout, int n) {
    __shared__ float sc[128], sf[128];
    int t = threadIdx.x;
    if (t < 128) {
        float m = sums[t] * (1.f / N_NODES);
        float var = sums[128 + t] * (1.f / N_NODES) - m * m;
        float s = g[t] * rsqrtf(var + BN_EPS);
        sc[t] = s;
        sf[t] = b[t] - m * s;
    }
    __syncthreads();
    int idx = blockIdx.x * blockDim.x + t;
    int total = n * 16;   // uint4 per row = 16 (8 bf16 each)
    float alpha = a[0];
    for (; idx < total; idx += gridDim.x * blockDim.x) {
        int c0 = (idx & 15) * 8;
        uint4 v = y4[idx];
        unsigned int* vu = (unsigned int*)&v;
        uint4 o;
        unsigned int* ou = (unsigned int*)&o;
        #pragma unroll
        for (int u = 0; u < 4; ++u) {
            int c = c0 + u * 2;
            float lo = bf_lo(vu[u]) * sc[c] + sf[c];
            float hi = bf_hi(vu[u]) * sc[c + 1] + sf[c + 1];
            lo = lo >= 0.f ? lo : alpha * lo;
            hi = hi >= 0.f ? hi : alpha * hi;
            ou[u] = (unsigned int)f2bf(lo) | ((unsigned int)f2bf(hi) << 16);
        }
        xout[idx] = o;
    }
}

// ---------------- pooling + classifier ----------------

__global__ void pool_kernel(const unsigned short* __restrict__ h, const int* __restrict__ g_start,
                            float* __restrict__ pooled) {
    int g = blockIdx.x >> 3, part = blockIdx.x & 7;
    int d = threadIdx.x;  // 128
    int s = g_start[g], e = g_start[g + 1];
    int len = e - s;
    int ps = s + ((len * part) >> 3), pe = s + ((len * (part + 1)) >> 3);
    float acc = 0.f;
    for (int i = ps; i < pe; ++i) {
        unsigned short v = h[(size_t)i * DIM + d];
        acc += __uint_as_float(((unsigned int)v) << 16);
    }
    atomicAdd(&pooled[g * DIM + d], acc);
}

__global__ void final_kernel(const float* __restrict__ pooled, const int* __restrict__ g_start,
                             const float* __restrict__ Wf, const float* __restrict__ bf,
                             float* __restrict__ out) {
    int idx = blockIdx.x * 256 + threadIdx.x;  // 2048 = 64 groups x 32 classes
    int g = idx >> 5, c = idx & 31;
    int cnt = g_start[g + 1] - g_start[g];
    float inv = 1.f / (float)(cnt > 0 ? cnt : 1);
    float acc = 0.f;
    for (int dd = 0; dd < 128; ++dd) acc += pooled[g * DIM + dd] * Wf[c * DIM + dd];
    out[idx] = acc * inv + bf[c];
}

// ---------------- launcher ----------------

extern "C" void kernel_launch(void* const* d_in, const int* in_sizes, int n_in,
                              void* d_out, int out_size, void* d_ws, size_t ws_size,
                              hipStream_t stream) {
    const float* x = (const float*)d_in[0];
    const int* ei = (const int*)d_in[1];
    const int* batch = (const int*)d_in[2];
    const float* Wl[3] = {(const float*)d_in[3], (const float*)d_in[9], (const float*)d_in[15]};
    const float* bl[3] = {(const float*)d_in[4], (const float*)d_in[10], (const float*)d_in[16]};
    const float* Wr[3] = {(const float*)d_in[5], (const float*)d_in[11], (const float*)d_in[17]};
    const float* gg[3] = {(const float*)d_in[6], (const float*)d_in[12], (const float*)d_in[18]};
    const float* bb[3] = {(const float*)d_in[7], (const float*)d_in[13], (const float*)d_in[19]};
    const float* aa[3] = {(const float*)d_in[8], (const float*)d_in[14], (const float*)d_in[20]};
    const float* Wjk = (const float*)d_in[21];
    const float* bjk = (const float*)d_in[22];
    const float* Wf = (const float*)d_in[23];
    const float* bf = (const float*)d_in[24];
    float* out = (float*)d_out;

    char* ws = (char*)d_ws;
    size_t off = 0;
    auto alloc = [&](size_t bytes) {
        void* p = ws + off;
        off += (bytes + 255) & ~(size_t)255;
        return p;
    };
    // ---- contiguous zero region: cnt8 | scan_status | pooled | sums x3 ----
    size_t zero_begin = off;
    int* cnt8 = (int*)alloc((size_t)8 * CPY * 4);
    unsigned int* scan_status = (unsigned int*)alloc(SCAN_BLOCKS * 4);
    float* pooled = (float*)alloc(NGROUPS * DIM * 4);
    float* sums0 = (float*)alloc(256 * 4);
    float* sums1 = (float*)alloc(256 * 4);
    float* sums2 = (float*)alloc(256 * 4);
    size_t zero_bytes = off - zero_begin;
    float* sums_l[3] = {sums0, sums1, sums2};
    // ---- rest ----
    int* pos_e = (int*)alloc((size_t)N_EDGES * 4);
    int* row_start = (int*)alloc((N_NODES + 1) * 4);
    int* start8 = (int*)alloc((size_t)8 * CPY * 4);
    int* csr = (int*)alloc((size_t)N_EDGES * 4);
    int* g_start = (int*)alloc((NGROUPS + 1) * 4);
    unsigned short* Y = (unsigned short*)alloc((size_t)N_NODES * DIM * 2);
    unsigned short* X0 = (unsigned short*)alloc((size_t)N_NODES * DIM * 2);
    unsigned short* X1 = (unsigned short*)alloc((size_t)N_NODES * DIM * 2);
    unsigned short* X2 = (unsigned short*)alloc((size_t)N_NODES * DIM * 2);
    unsigned short* AGGb = (unsigned short*)alloc((size_t)N_NODES * DIM * 2);
    unsigned short* Wb = (unsigned short*)alloc((size_t)9 * 16384 * 2);
    unsigned short* Wlb[3] = {Wb, Wb + 2 * 16384, Wb + 4 * 16384};
    unsigned short* Wrb[3] = {Wb + 16384, Wb + 3 * 16384, Wb + 5 * 16384};
    unsigned short* Wjkb = Wb + 6 * 16384;
    unsigned short* Xl[2] = {X1, X2};

    hipMemsetAsync(ws + zero_begin, 0, zero_bytes, stream);

    prep_kernel<<<PREP_TOTAL, 256, 0, stream>>>(ei, cnt8, pos_e, batch, g_start, x,
                                                (unsigned int*)X0,
                                                Wl[0], Wr[0], Wl[1], Wr[1], Wl[2], Wr[2], Wb,
                                                Wjk, Wjkb);
    scan_kernel<<<SCAN_BLOCKS, 256, 0, stream>>>(cnt8, row_start, start8, scan_status);
    fill_kernel<<<PREP_COUNT, 256, 0, stream>>>(ei, pos_e, start8, csr);

    const int NBLK = (N_NODES + 127) / 128;   // 391
    const int NBLK64 = (N_NODES + 63) / 64;   // 782
    const unsigned short* xin = X0;
    for (int l = 0; l < 3; ++l) {
        agg_kernel<<<N_NODES / 4, 256, 0, stream>>>(xin, csr, row_start, AGGb);
        mfma_linear<2, 128, 0, 1, 0><<<NBLK, 256, 0, stream>>>(
            AGGb, xin, nullptr, Wlb[l], Wrb[l], nullptr, bl[l], Y, sums_l[l],
            nullptr, nullptr, nullptr, nullptr, N_NODES);
        if (l < 2) {
            bn_apply_kernel<<<2048, 256, 0, stream>>>(
                (const uint4*)Y, sums_l[l], gg[l], bb[l], aa[l], (uint4*)Xl[l], N_NODES);
            xin = Xl[l];
        }
    }

    // JK: Y = relu(X1@Wjk0^T + X2@Wjk1^T + BN3(Y)@Wjk2^T + bjk) — BN3+PReLU fused on A2
    mfma_linear<3, 64, 1, 0, 1><<<NBLK64, 256, 0, stream>>>(
        X1, X2, Y, Wjkb, Wjkb + 16384, Wjkb + 2 * 16384, bjk, Y, nullptr,
        sums2, gg[2], bb[2], aa[2], N_NODES);

    pool_kernel<<<NGROUPS * 8, 128, 0, stream>>>(Y, g_start, pooled);
    final_kernel<<<8, 256, 0, stream>>>(pooled, g_start, Wf, bf, out);
}

// Round 12
// 417.404 us; speedup vs baseline: 1.0831x; 1.0831x over previous
//
#include <hip/hip_runtime.h>

#define N_NODES 50000
#define N_EDGES 800000
#define DIM 128
#define NGROUPS 64
#define NCLS 32
#define BN_EPS 1e-5f
#define NPART_PAD 800   // >= 2*NBLK (782)
#define SCAN_BLOCKS 98  // ceil(50000/512)
#define CPY 50048       // padded per-copy stride

// prep grid layout
#define PREP_COUNT 3125
#define PREP_GSTART (PREP_COUNT + 196)   // 3321
#define PREP_CONVX (PREP_GSTART + 2048)  // 5369
#define PREP_W6 (PREP_CONVX + 384)       // 5753
#define PREP_TOTAL (PREP_W6 + 192)       // 5945

typedef short short8_t __attribute__((ext_vector_type(8)));
typedef float f32x4 __attribute__((ext_vector_type(4)));
typedef const __attribute__((address_space(1))) unsigned char* gptr_t;
typedef __attribute__((address_space(3))) unsigned char* sptr_t;

__device__ __forceinline__ unsigned short f2bf(float f) {
    unsigned int u = __float_as_uint(f);
    u += 0x7FFFu + ((u >> 16) & 1u);   // round-to-nearest-even
    return (unsigned short)(u >> 16);
}
__device__ __forceinline__ float bf_lo(unsigned int u) { return __uint_as_float(u << 16); }
__device__ __forceinline__ float bf_hi(unsigned int u) { return __uint_as_float(u & 0xffff0000u); }

// ---------------- fused prep: count (8 privatized copies, emits pos_e) + gstart + converts ----

__global__ __launch_bounds__(256) void prep_kernel(
    const int* __restrict__ ei, int* __restrict__ cnt8, int* __restrict__ pos_e,
    const int* __restrict__ batch, int* __restrict__ g_start,
    const float* __restrict__ x, unsigned int* __restrict__ X0,
    const float* w0, const float* w1, const float* w2,
    const float* w3, const float* w4, const float* w5,
    unsigned short* __restrict__ Wb,
    const float* __restrict__ Wjk, unsigned short* __restrict__ Wjkb) {
    int b = blockIdx.x, t = threadIdx.x;
    if (b < PREP_COUNT) {
        int e = b * 256 + t;   // 3125*256 == 800000 exactly
        int dst = ei[N_EDGES + e];
        pos_e[e] = atomicAdd(&cnt8[(b & 7) * CPY + dst], 1);
    } else if (b < PREP_GSTART) {
        int i = (b - PREP_COUNT) * 256 + t;
        if (i < N_NODES) {
            int bb = batch[i];
            if (i == 0) {
                for (int g = 0; g <= bb; ++g) g_start[g] = 0;
            } else {
                int p = batch[i - 1];
                for (int g = p + 1; g <= bb; ++g) g_start[g] = i;
            }
            if (i == N_NODES - 1) {
                for (int g = bb + 1; g <= NGROUPS; ++g) g_start[g] = N_NODES;
            }
        }
    } else if (b < PREP_CONVX) {
        const float4* s4 = (const float4*)x;
        const int total4 = N_NODES * 32;
        for (int idx = (b - PREP_GSTART) * 256 + t; idx < total4; idx += 2048 * 256) {
            float4 v = s4[idx];
            X0[idx * 2] = (unsigned int)f2bf(v.x) | ((unsigned int)f2bf(v.y) << 16);
            X0[idx * 2 + 1] = (unsigned int)f2bf(v.z) | ((unsigned int)f2bf(v.w) << 16);
        }
    } else if (b < PREP_W6) {
        int idx = (b - PREP_CONVX) * 256 + t;   // 0 .. 6*16384
        int mat = idx >> 14, off = idx & 16383;
        const float* s = (mat == 0) ? w0 : (mat == 1) ? w1 : (mat == 2) ? w2
                       : (mat == 3) ? w3 : (mat == 4) ? w4 : w5;
        Wb[idx] = f2bf(s[off]);
    } else {
        int idx = (b - PREP_W6) * 256 + t;   // 0 .. 49152
        int d = idx / 384, k = idx - d * 384;
        int part = k >> 7, kk = k & 127;
        Wjkb[part * 16384 + d * 128 + kk] = f2bf(Wjk[idx]);
    }
}

// ---------------- decoupled-lookback scan over 8 copies; emits per-copy sub-offsets ----------------

#define FLG_AGG 0x40000000u
#define FLG_PFX 0x80000000u
#define FLG_VAL 0x3FFFFFFFu

__global__ __launch_bounds__(256) void scan_kernel(const int* __restrict__ cnt8,
                                                   int* __restrict__ row_start,
                                                   int* __restrict__ start8,
                                                   unsigned int* __restrict__ status) {
    int b = blockIdx.x, t = threadIdx.x;
    int idx = b * 512 + 2 * t;
    int c0[8], c1[8];
    int v0 = 0, v1 = 0;
    if (idx + 1 < N_NODES) {
        #pragma unroll
        for (int q = 0; q < 8; ++q) {
            int2 p = ((const int2*)(cnt8 + q * CPY))[b * 256 + t];
            c0[q] = p.x; c1[q] = p.y;
            v0 += p.x; v1 += p.y;
        }
    } else if (idx < N_NODES) {
        #pragma unroll
        for (int q = 0; q < 8; ++q) {
            c0[q] = cnt8[q * CPY + idx]; c1[q] = 0;
            v0 += c0[q];
        }
    } else {
        #pragma unroll
        for (int q = 0; q < 8; ++q) { c0[q] = 0; c1[q] = 0; }
    }
    int pair = v0 + v1;
    int lane = t & 63, w = t >> 6;
    int x = pair;
    #pragma unroll
    for (int off = 1; off < 64; off <<= 1) {
        int t2 = __shfl_up(x, off);
        if (lane >= off) x += t2;
    }
    __shared__ int wtot[4], wexcl[4];
    __shared__ int s_tot;
    __shared__ unsigned int s_run;
    if (lane == 63) wtot[w] = x;
    __syncthreads();
    if (t == 0) {
        int c = 0;
        #pragma unroll
        for (int i = 0; i < 4; ++i) { wexcl[i] = c; c += wtot[i]; }
        s_tot = c;
        unsigned int pub = (b == 0) ? (FLG_PFX | (unsigned int)c) : (FLG_AGG | (unsigned int)c);
        atomicExch(&status[b], pub);
    }
    __syncthreads();
    int total = s_tot;
    if (t == 0) {
        unsigned int run = 0;
        if (b > 0) {
            int i = b - 1;
            while (true) {
                unsigned int s = atomicAdd(&status[i], 0u);
                if (s & FLG_PFX) { run += s & FLG_VAL; break; }
                if (s & FLG_AGG) { run += s & FLG_VAL; --i; }
            }
            atomicExch(&status[b], FLG_PFX | (run + (unsigned int)total));
        }
        s_run = run;
    }
    __syncthreads();
    int gexcl = (int)s_run + wexcl[w] + (x - pair);
    if (idx < N_NODES) {
        row_start[idx] = gexcl;
        int run = gexcl;
        #pragma unroll
        for (int q = 0; q < 8; ++q) { start8[q * CPY + idx] = run; run += c0[q]; }
    }
    if (idx + 1 < N_NODES) {
        int g1 = gexcl + v0;
        row_start[idx + 1] = g1;
        int run = g1;
        #pragma unroll
        for (int q = 0; q < 8; ++q) { start8[q * CPY + idx + 1] = run; run += c1[q]; }
    }
    if (b == 0 && t == 0) row_start[N_NODES] = N_EDGES;
}

// ---------------- fill: atomic-free (positions precomputed in prep) ----------------

__global__ __launch_bounds__(256) void fill_kernel(const int* __restrict__ ei,
                                                   const int* __restrict__ pos_e,
                                                   const int* __restrict__ start8,
                                                   int* __restrict__ csr) {
    int b = blockIdx.x;   // 3125
    int e = b * 256 + threadIdx.x;
    int dst = ei[N_EDGES + e];
    csr[start8[(b & 7) * CPY + dst] + pos_e[e]] = ei[e];
}

// ---------------- mean aggregation: 16 lanes/row x 4 edges x 4-deep ILP (proven best) ------

#define ACC8(u)                                                                           \
    do {                                                                                  \
        a[0] += bf_lo((u).x); a[1] += bf_hi((u).x);                                        \
        a[2] += bf_lo((u).y); a[3] += bf_hi((u).y);                                        \
        a[4] += bf_lo((u).z); a[5] += bf_hi((u).z);                                        \
        a[6] += bf_lo((u).w); a[7] += bf_hi((u).w);                                        \
    } while (0)

__global__ __launch_bounds__(256) void agg_kernel(const unsigned short* __restrict__ xin,
                                                  const int* __restrict__ csr,
                                                  const int* __restrict__ row_start,
                                                  unsigned short* __restrict__ out) {
    int node = blockIdx.x * 4 + (threadIdx.x >> 6);
    int lane = threadIdx.x & 63;
    int g = lane >> 4, s16 = lane & 15;
    const uint4* base = (const uint4*)xin;   // one row = 16 uint4
    int cs = row_start[node], ce = row_start[node + 1];
    float a[8] = {0.f, 0.f, 0.f, 0.f, 0.f, 0.f, 0.f, 0.f};
    int i = cs;
    for (; i + 16 <= ce; i += 16) {
        int e0 = csr[i + g], e1 = csr[i + 4 + g], e2 = csr[i + 8 + g], e3 = csr[i + 12 + g];
        uint4 u0 = base[e0 * 16 + s16];
        uint4 u1 = base[e1 * 16 + s16];
        uint4 u2 = base[e2 * 16 + s16];
        uint4 u3 = base[e3 * 16 + s16];
        ACC8(u0); ACC8(u1); ACC8(u2); ACC8(u3);
    }
    if (i + 8 <= ce) {
        int e0 = csr[i + g], e1 = csr[i + 4 + g];
        uint4 u0 = base[e0 * 16 + s16];
        uint4 u1 = base[e1 * 16 + s16];
        ACC8(u0); ACC8(u1);
        i += 8;
    }
    if (i + 4 <= ce) {
        int e0 = csr[i + g];
        uint4 u0 = base[e0 * 16 + s16];
        ACC8(u0);
        i += 4;
    }
    if (i + g < ce) {
        int e0 = csr[i + g];
        uint4 u0 = base[e0 * 16 + s16];
        ACC8(u0);
    }
    #pragma unroll
    for (int k = 0; k < 8; ++k) {
        a[k] += __shfl_xor(a[k], 16);
        a[k] += __shfl_xor(a[k], 32);
    }
    if (g == 0) {
        int deg = ce - cs;
        float inv = 1.f / (float)(deg > 0 ? deg : 1);
        uint4 p;
        p.x = (unsigned int)f2bf(a[0] * inv) | ((unsigned int)f2bf(a[1] * inv) << 16);
        p.y = (unsigned int)f2bf(a[2] * inv) | ((unsigned int)f2bf(a[3] * inv) << 16);
        p.z = (unsigned int)f2bf(a[4] * inv) | ((unsigned int)f2bf(a[5] * inv) << 16);
        p.w = (unsigned int)f2bf(a[6] * inv) | ((unsigned int)f2bf(a[7] * inv) << 16);
        ((uint4*)out)[node * 16 + s16] = p;
    }
}

// ---------------- MFMA linear: C(bf16) = sum_p A_p @ W_p^T + bias [relu] ----------------
// STATS: per-block column sum/sumsq written transposed (non-atomic):
//        partials[col*2*NPART_PAD + part], partials[col*2*NPART_PAD + NPART_PAD + part].
// BNFUSE: A_{P-1} is raw (pre-BN) — apply per-column affine+PReLU to its fragments,
//         coefs (scale/shift) read from coef_in[0..127]/[128..255] into LDS.

template <int P, int ROWS, int RELU, int STATS, int BNFUSE>
__global__ __launch_bounds__(256, 2) void mfma_linear(
    const unsigned short* __restrict__ A0, const unsigned short* __restrict__ A1,
    const unsigned short* __restrict__ A2,
    const unsigned short* __restrict__ W0, const unsigned short* __restrict__ W1,
    const unsigned short* __restrict__ W2,
    const float* __restrict__ bias, unsigned short* __restrict__ C,
    float* __restrict__ partials,
    const float* __restrict__ coef_in, const float* __restrict__ bn_a,
    int n_rows) {
    constexpr int S = P * 16;          // 16B slots per LDS row
    constexpr int MR = ROWS / 32;      // m-frags per wave
    __shared__ char lds[ROWS * P * 256];
    __shared__ float csc[128], csf[128];
    int t = threadIdx.x;
    int lane = t & 63;
    int wr = (t >> 7) & 1, wc = (t >> 6) & 1;
    int row_base = blockIdx.x * ROWS;

    // stage activations: LDS linear dest, swizzled global source
    #pragma unroll
    for (int c = 0; c < (ROWS * S) / 256; ++c) {
        int flat = c * 256 + t;
        int row = flat / S;
        int s = flat - row * S;
        int ss = s ^ (row & 7);
        int grow = row_base + row;
        if (grow >= n_rows) grow = n_rows - 1;
        const unsigned short* Ap = (ss < 16) ? A0 : (ss < 32 ? A1 : A2);
        const unsigned short* srcp = Ap + (size_t)grow * 128 + (ss & 15) * 8;
        __builtin_amdgcn_global_load_lds((gptr_t)srcp, (sptr_t)(lds + flat * 16), 16, 0, 0);
    }

    float alpha = 0.f;
    if (BNFUSE) {
        if (t < 128) {
            csc[t] = coef_in[t];
            csf[t] = coef_in[128 + t];
        }
        alpha = bn_a[0];
    }

    const unsigned short* Wp[3] = {W0, W1, W2};
    short8_t bcur[4][4], bnxt[4][4];
    #pragma unroll
    for (int ksp = 0; ksp < 4; ++ksp)
        #pragma unroll
        for (int nn = 0; nn < 4; ++nn) {
            int col = wc * 64 + nn * 16 + (lane & 15);
            int k0 = ksp * 32 + (lane >> 4) * 8;
            bcur[ksp][nn] = *(const short8_t*)(W0 + col * 128 + k0);
        }

    f32x4 acc[MR][4];
    #pragma unroll
    for (int m = 0; m < MR; ++m)
        #pragma unroll
        for (int nn = 0; nn < 4; ++nn)
            acc[m][nn] = (f32x4){0.f, 0.f, 0.f, 0.f};

    __syncthreads();   // drains vmcnt (global_load_lds); csc/csf visible

    #pragma unroll
    for (int p = 0; p < P; ++p) {
        if (p + 1 < P) {
            #pragma unroll
            for (int ksp = 0; ksp < 4; ++ksp)
                #pragma unroll
                for (int nn = 0; nn < 4; ++nn) {
                    int col = wc * 64 + nn * 16 + (lane & 15);
                    int k0 = ksp * 32 + (lane >> 4) * 8;
                    bnxt[ksp][nn] = *(const short8_t*)(Wp[p + 1] + col * 128 + k0);
                }
        }
        #pragma unroll
        for (int ksp = 0; ksp < 4; ++ksp) {
            int ks = p * 4 + ksp;
            short8_t a[MR];
            #pragma unroll
            for (int m = 0; m < MR; ++m) {
                int row = wr * (ROWS / 2) + m * 16 + (lane & 15);
                int s = ks * 4 + (lane >> 4);
                int off = row * (P * 256) + ((s ^ (row & 7)) * 16);
                a[m] = *(const short8_t*)(lds + off);
            }
            if (BNFUSE && p == P - 1) {
                int c0 = ksp * 32 + (lane >> 4) * 8;   // local column in A_{P-1}
                #pragma unroll
                for (int m = 0; m < MR; ++m) {
                    unsigned int* au = (unsigned int*)&a[m];
                    #pragma unroll
                    for (int u = 0; u < 4; ++u) {
                        int c = c0 + u * 2;
                        float lo = bf_lo(au[u]) * csc[c] + csf[c];
                        float hi = bf_hi(au[u]) * csc[c + 1] + csf[c + 1];
                        lo = lo >= 0.f ? lo : alpha * lo;
                        hi = hi >= 0.f ? hi : alpha * hi;
                        au[u] = (unsigned int)f2bf(lo) | ((unsigned int)f2bf(hi) << 16);
                    }
                }
            }
            #pragma unroll
            for (int m = 0; m < MR; ++m)
                #pragma unroll
                for (int nn = 0; nn < 4; ++nn)
                    acc[m][nn] = __builtin_amdgcn_mfma_f32_16x16x32_bf16(a[m], bcur[ksp][nn], acc[m][nn], 0, 0, 0);
        }
        if (p + 1 < P) {
            #pragma unroll
            for (int ksp = 0; ksp < 4; ++ksp)
                #pragma unroll
                for (int nn = 0; nn < 4; ++nn)
                    bcur[ksp][nn] = bnxt[ksp][nn];
        }
    }

    // epilogue: bias [+relu], bf16 store (+ per-block BN partial stats, non-atomic)
    #pragma unroll
    for (int nn = 0; nn < 4; ++nn) {
        int col = wc * 64 + nn * 16 + (lane & 15);
        float badd = bias[col];
        float ps = 0.f, pq = 0.f;
        #pragma unroll
        for (int m = 0; m < MR; ++m) {
            #pragma unroll
            for (int j = 0; j < 4; ++j) {
                int row = row_base + wr * (ROWS / 2) + m * 16 + (lane >> 4) * 4 + j;
                if (row < n_rows) {
                    float v = acc[m][nn][j] + badd;
                    if (RELU) v = fmaxf(v, 0.f);
                    C[(size_t)row * 128 + col] = f2bf(v);
                    if (STATS) { ps += v; pq += v * v; }
                }
            }
        }
        if (STATS) {
            ps += __shfl_xor(ps, 16); ps += __shfl_xor(ps, 32);
            pq += __shfl_xor(pq, 16); pq += __shfl_xor(pq, 32);
            if (lane < 16) {
                int part = blockIdx.x * 2 + wr;
                partials[col * 2 * NPART_PAD + part] = ps;
                partials[col * 2 * NPART_PAD + NPART_PAD + part] = pq;
            }
        }
    }
}

// ---------------- BN: reduce partials -> coefs (one block per column) ----------------

__global__ __launch_bounds__(256) void bn_reduce_kernel(const float* __restrict__ partials,
                                                        const float* __restrict__ g,
                                                        const float* __restrict__ b,
                                                        float* __restrict__ coef,
                                                        int npart, float invn) {
    int c = blockIdx.x;   // 128 blocks, one column each
    int t = threadIdx.x;
    const float* ps = partials + (size_t)c * 2 * NPART_PAD;
    float s = 0.f, q = 0.f;
    for (int r = t; r < npart; r += 256) {
        s += ps[r];
        q += ps[NPART_PAD + r];
    }
    #pragma unroll
    for (int off = 1; off < 64; off <<= 1) {
        s += __shfl_xor(s, off);
        q += __shfl_xor(q, off);
    }
    __shared__ float sh[8];
    int w = t >> 6;
    if ((t & 63) == 0) { sh[w] = s; sh[4 + w] = q; }
    __syncthreads();
    if (t == 0) {
        float S = sh[0] + sh[1] + sh[2] + sh[3];
        float Q = sh[4] + sh[5] + sh[6] + sh[7];
        float m = S * invn;
        float var = Q * invn - m * m;
        float sc = g[c] * rsqrtf(var + BN_EPS);
        coef[c] = sc;
        coef[128 + c] = b[c] - m * sc;
    }
}

// ---------------- BN apply: bf16 Y in, bf16 X out (coefs precomputed) ----------------

__global__ void bn_apply_kernel(const uint4* __restrict__ y4, const float* __restrict__ coef,
                                const float* __restrict__ a, uint4* __restrict__ xout, int n) {
    int idx = blockIdx.x * blockDim.x + threadIdx.x;
    int total = n * 16;   // uint4 per row = 16 (8 bf16 each)
    float alpha = a[0];
    const float4* c4 = (const float4*)coef;
    for (; idx < total; idx += gridDim.x * blockDim.x) {
        int d = idx & 15;
        uint4 v = y4[idx];
        float4 sc0 = c4[d * 2], sc1 = c4[d * 2 + 1];
        float4 sf0 = c4[32 + d * 2], sf1 = c4[32 + d * 2 + 1];
        float r0 = bf_lo(v.x) * sc0.x + sf0.x;
        float r1 = bf_hi(v.x) * sc0.y + sf0.y;
        float r2 = bf_lo(v.y) * sc0.z + sf0.z;
        float r3 = bf_hi(v.y) * sc0.w + sf0.w;
        float r4 = bf_lo(v.z) * sc1.x + sf1.x;
        float r5 = bf_hi(v.z) * sc1.y + sf1.y;
        float r6 = bf_lo(v.w) * sc1.z + sf1.z;
        float r7 = bf_hi(v.w) * sc1.w + sf1.w;
        r0 = r0 >= 0.f ? r0 : alpha * r0;
        r1 = r1 >= 0.f ? r1 : alpha * r1;
        r2 = r2 >= 0.f ? r2 : alpha * r2;
        r3 = r3 >= 0.f ? r3 : alpha * r3;
        r4 = r4 >= 0.f ? r4 : alpha * r4;
        r5 = r5 >= 0.f ? r5 : alpha * r5;
        r6 = r6 >= 0.f ? r6 : alpha * r6;
        r7 = r7 >= 0.f ? r7 : alpha * r7;
        uint4 o;
        o.x = (unsigned int)f2bf(r0) | ((unsigned int)f2bf(r1) << 16);
        o.y = (unsigned int)f2bf(r2) | ((unsigned int)f2bf(r3) << 16);
        o.z = (unsigned int)f2bf(r4) | ((unsigned int)f2bf(r5) << 16);
        o.w = (unsigned int)f2bf(r6) | ((unsigned int)f2bf(r7) << 16);
        xout[idx] = o;
    }
}

// ---------------- pooling + classifier ----------------

__global__ void pool_kernel(const unsigned short* __restrict__ h, const int* __restrict__ g_start,
                            float* __restrict__ pooled) {
    int g = blockIdx.x >> 3, part = blockIdx.x & 7;
    int d = threadIdx.x;  // 128
    int s = g_start[g], e = g_start[g + 1];
    int len = e - s;
    int ps = s + ((len * part) >> 3), pe = s + ((len * (part + 1)) >> 3);
    float acc = 0.f;
    for (int i = ps; i < pe; ++i) {
        unsigned short v = h[(size_t)i * DIM + d];
        acc += __uint_as_float(((unsigned int)v) << 16);
    }
    atomicAdd(&pooled[g * DIM + d], acc);
}

__global__ void final_kernel(const float* __restrict__ pooled, const int* __restrict__ g_start,
                             const float* __restrict__ Wf, const float* __restrict__ bf,
                             float* __restrict__ out) {
    int idx = blockIdx.x * 256 + threadIdx.x;  // 2048 = 64 groups x 32 classes
    int g = idx >> 5, c = idx & 31;
    int cnt = g_start[g + 1] - g_start[g];
    float inv = 1.f / (float)(cnt > 0 ? cnt : 1);
    float acc = 0.f;
    for (int dd = 0; dd < 128; ++dd) acc += pooled[g * DIM + dd] * Wf[c * DIM + dd];
    out[idx] = acc * inv + bf[c];
}

// ---------------- launcher ----------------

extern "C" void kernel_launch(void* const* d_in, const int* in_sizes, int n_in,
                              void* d_out, int out_size, void* d_ws, size_t ws_size,
                              hipStream_t stream) {
    const float* x = (const float*)d_in[0];
    const int* ei = (const int*)d_in[1];
    const int* batch = (const int*)d_in[2];
    const float* Wl[3] = {(const float*)d_in[3], (const float*)d_in[9], (const float*)d_in[15]};
    const float* bl[3] = {(const float*)d_in[4], (const float*)d_in[10], (const float*)d_in[16]};
    const float* Wr[3] = {(const float*)d_in[5], (const float*)d_in[11], (const float*)d_in[17]};
    const float* gg[3] = {(const float*)d_in[6], (const float*)d_in[12], (const float*)d_in[18]};
    const float* bb[3] = {(const float*)d_in[7], (const float*)d_in[13], (const float*)d_in[19]};
    const float* aa[3] = {(const float*)d_in[8], (const float*)d_in[14], (const float*)d_in[20]};
    const float* Wjk = (const float*)d_in[21];
    const float* bjk = (const float*)d_in[22];
    const float* Wf = (const float*)d_in[23];
    const float* bf = (const float*)d_in[24];
    float* out = (float*)d_out;

    char* ws = (char*)d_ws;
    size_t off = 0;
    auto alloc = [&](size_t bytes) {
        void* p = ws + off;
        off += (bytes + 255) & ~(size_t)255;
        return p;
    };
    // ---- contiguous zero region: cnt8 | scan_status | pooled ----
    size_t zero_begin = off;
    int* cnt8 = (int*)alloc((size_t)8 * CPY * 4);
    unsigned int* scan_status = (unsigned int*)alloc(SCAN_BLOCKS * 4);
    float* pooled = (float*)alloc(NGROUPS * DIM * 4);
    size_t zero_bytes = off - zero_begin;
    // ---- rest ----
    int* pos_e = (int*)alloc((size_t)N_EDGES * 4);
    int* row_start = (int*)alloc((N_NODES + 1) * 4);
    int* start8 = (int*)alloc((size_t)8 * CPY * 4);
    int* csr = (int*)alloc((size_t)N_EDGES * 4);
    int* g_start = (int*)alloc((NGROUPS + 1) * 4);
    float* bn_part = (float*)alloc((size_t)128 * 2 * NPART_PAD * 4);
    float* bn_coef = (float*)alloc(256 * 4);
    unsigned short* Y = (unsigned short*)alloc((size_t)N_NODES * DIM * 2);
    unsigned short* X0 = (unsigned short*)alloc((size_t)N_NODES * DIM * 2);
    unsigned short* X1 = (unsigned short*)alloc((size_t)N_NODES * DIM * 2);
    unsigned short* X2 = (unsigned short*)alloc((size_t)N_NODES * DIM * 2);
    unsigned short* AGGb = (unsigned short*)alloc((size_t)N_NODES * DIM * 2);
    unsigned short* Wb = (unsigned short*)alloc((size_t)9 * 16384 * 2);
    unsigned short* Wlb[3] = {Wb, Wb + 2 * 16384, Wb + 4 * 16384};
    unsigned short* Wrb[3] = {Wb + 16384, Wb + 3 * 16384, Wb + 5 * 16384};
    unsigned short* Wjkb = Wb + 6 * 16384;
    unsigned short* Xl[2] = {X1, X2};

    hipMemsetAsync(ws + zero_begin, 0, zero_bytes, stream);

    prep_kernel<<<PREP_TOTAL, 256, 0, stream>>>(ei, cnt8, pos_e, batch, g_start, x,
                                                (unsigned int*)X0,
                                                Wl[0], Wr[0], Wl[1], Wr[1], Wl[2], Wr[2], Wb,
                                                Wjk, Wjkb);
    scan_kernel<<<SCAN_BLOCKS, 256, 0, stream>>>(cnt8, row_start, start8, scan_status);
    fill_kernel<<<PREP_COUNT, 256, 0, stream>>>(ei, pos_e, start8, csr);

    const int NBLK = (N_NODES + 127) / 128;   // 391
    const int NBLK64 = (N_NODES + 63) / 64;   // 782
    const unsigned short* xin = X0;
    for (int l = 0; l < 3; ++l) {
        agg_kernel<<<N_NODES / 4, 256, 0, stream>>>(xin, csr, row_start, AGGb);
        mfma_linear<2, 128, 0, 1, 0><<<NBLK, 256, 0, stream>>>(
            AGGb, xin, nullptr, Wlb[l], Wrb[l], nullptr, bl[l], Y, bn_part,
            nullptr, nullptr, N_NODES);
        bn_reduce_kernel<<<128, 256, 0, stream>>>(bn_part, gg[l], bb[l], bn_coef, 2 * NBLK, 1.f / N_NODES);
        if (l < 2) {
            bn_apply_kernel<<<2048, 256, 0, stream>>>(
                (const uint4*)Y, bn_coef, aa[l], (uint4*)Xl[l], N_NODES);
            xin = Xl[l];
        }
    }

    // JK: Y = relu(X1@Wjk0^T + X2@Wjk1^T + BN3(Y)@Wjk2^T + bjk) — BN3+PReLU fused on A2,
    // coefs precomputed by layer-3 bn_reduce.
    mfma_linear<3, 64, 1, 0, 1><<<NBLK64, 256, 0, stream>>>(
        X1, X2, Y, Wjkb, Wjkb + 16384, Wjkb + 2 * 16384, bjk, Y, nullptr,
        bn_coef, aa[2], N_NODES);

    pool_kernel<<<NGROUPS * 8, 128, 0, stream>>>(Y, g_start, pooled);
    final_kernel<<<8, 256, 0, stream>>>(pooled, g_start, Wf, bf, out);
}

// Round 13
// 391.973 us; speedup vs baseline: 1.1533x; 1.0649x over previous
//
#include <hip/hip_runtime.h>

#define N_NODES 50000
#define N_EDGES 800000
#define DIM 128
#define NGROUPS 64
#define NCLS 32
#define BN_EPS 1e-5f
#define NPART_PAD 1600  // >= 2*NBLK64 (1564)
#define SCAN_BLOCKS 98  // ceil(50000/512)
#define CPY 50048       // padded per-copy stride

// prep grid layout
#define PREP_COUNT 3125
#define PREP_GSTART (PREP_COUNT + 196)   // 3321
#define PREP_CONVX (PREP_GSTART + 2048)  // 5369
#define PREP_W6 (PREP_CONVX + 384)       // 5753
#define PREP_TOTAL (PREP_W6 + 192)       // 5945

typedef short short8_t __attribute__((ext_vector_type(8)));
typedef float f32x4 __attribute__((ext_vector_type(4)));
typedef const __attribute__((address_space(1))) unsigned char* gptr_t;
typedef __attribute__((address_space(3))) unsigned char* sptr_t;

__device__ __forceinline__ unsigned short f2bf(float f) {
    unsigned int u = __float_as_uint(f);
    u += 0x7FFFu + ((u >> 16) & 1u);   // round-to-nearest-even
    return (unsigned short)(u >> 16);
}
__device__ __forceinline__ float bf_lo(unsigned int u) { return __uint_as_float(u << 16); }
__device__ __forceinline__ float bf_hi(unsigned int u) { return __uint_as_float(u & 0xffff0000u); }

// ---------------- fused prep: count + gstart + converts (weights -> fragment-major) ----------
// Wfrag layout per 128x128 matrix: elem[(kchunk*128 + col)*8 + j] = W[col*128 + kchunk*8 + j],
// kchunk in [0,16). A wave's 16-lane fragment load is then one contiguous 256B run.

__global__ __launch_bounds__(256) void prep_kernel(
    const int* __restrict__ ei, int* __restrict__ cnt8, int* __restrict__ pos_e,
    const int* __restrict__ batch, int* __restrict__ g_start,
    const float* __restrict__ x, unsigned int* __restrict__ X0,
    const float* w0, const float* w1, const float* w2,
    const float* w3, const float* w4, const float* w5,
    unsigned short* __restrict__ Wb,
    const float* __restrict__ Wjk, unsigned short* __restrict__ Wjkb) {
    int b = blockIdx.x, t = threadIdx.x;
    if (b < PREP_COUNT) {
        int e = b * 256 + t;   // 3125*256 == 800000 exactly
        int dst = ei[N_EDGES + e];
        pos_e[e] = atomicAdd(&cnt8[(b & 7) * CPY + dst], 1);
    } else if (b < PREP_GSTART) {
        int i = (b - PREP_COUNT) * 256 + t;
        if (i < N_NODES) {
            int bb = batch[i];
            if (i == 0) {
                for (int g = 0; g <= bb; ++g) g_start[g] = 0;
            } else {
                int p = batch[i - 1];
                for (int g = p + 1; g <= bb; ++g) g_start[g] = i;
            }
            if (i == N_NODES - 1) {
                for (int g = bb + 1; g <= NGROUPS; ++g) g_start[g] = N_NODES;
            }
        }
    } else if (b < PREP_CONVX) {
        const float4* s4 = (const float4*)x;
        const int total4 = N_NODES * 32;
        for (int idx = (b - PREP_GSTART) * 256 + t; idx < total4; idx += 2048 * 256) {
            float4 v = s4[idx];
            X0[idx * 2] = (unsigned int)f2bf(v.x) | ((unsigned int)f2bf(v.y) << 16);
            X0[idx * 2 + 1] = (unsigned int)f2bf(v.z) | ((unsigned int)f2bf(v.w) << 16);
        }
    } else if (b < PREP_W6) {
        int idx = (b - PREP_CONVX) * 256 + t;   // 0 .. 6*16384
        int mat = idx >> 14, o = idx & 16383;
        const float* s = (mat == 0) ? w0 : (mat == 1) ? w1 : (mat == 2) ? w2
                       : (mat == 3) ? w3 : (mat == 4) ? w4 : w5;
        int j = o & 7, col = (o >> 3) & 127, kchunk = (o >> 10) & 15;
        Wb[idx] = f2bf(s[col * 128 + kchunk * 8 + j]);
    } else {
        int idx = (b - PREP_W6) * 256 + t;   // 0 .. 49152
        int p = idx >> 14, o = idx & 16383;
        int j = o & 7, d = (o >> 3) & 127, kchunk = (o >> 10) & 15;
        Wjkb[idx] = f2bf(Wjk[d * 384 + p * 128 + kchunk * 8 + j]);
    }
}

// ---------------- decoupled-lookback scan over 8 copies; emits per-copy sub-offsets ----------------

#define FLG_AGG 0x40000000u
#define FLG_PFX 0x80000000u
#define FLG_VAL 0x3FFFFFFFu

__global__ __launch_bounds__(256) void scan_kernel(const int* __restrict__ cnt8,
                                                   int* __restrict__ row_start,
                                                   int* __restrict__ start8,
                                                   unsigned int* __restrict__ status) {
    int b = blockIdx.x, t = threadIdx.x;
    int idx = b * 512 + 2 * t;
    int c0[8], c1[8];
    int v0 = 0, v1 = 0;
    if (idx + 1 < N_NODES) {
        #pragma unroll
        for (int q = 0; q < 8; ++q) {
            int2 p = ((const int2*)(cnt8 + q * CPY))[b * 256 + t];
            c0[q] = p.x; c1[q] = p.y;
            v0 += p.x; v1 += p.y;
        }
    } else if (idx < N_NODES) {
        #pragma unroll
        for (int q = 0; q < 8; ++q) {
            c0[q] = cnt8[q * CPY + idx]; c1[q] = 0;
            v0 += c0[q];
        }
    } else {
        #pragma unroll
        for (int q = 0; q < 8; ++q) { c0[q] = 0; c1[q] = 0; }
    }
    int pair = v0 + v1;
    int lane = t & 63, w = t >> 6;
    int x = pair;
    #pragma unroll
    for (int off = 1; off < 64; off <<= 1) {
        int t2 = __shfl_up(x, off);
        if (lane >= off) x += t2;
    }
    __shared__ int wtot[4], wexcl[4];
    __shared__ int s_tot;
    __shared__ unsigned int s_run;
    if (lane == 63) wtot[w] = x;
    __syncthreads();
    if (t == 0) {
        int c = 0;
        #pragma unroll
        for (int i = 0; i < 4; ++i) { wexcl[i] = c; c += wtot[i]; }
        s_tot = c;
        unsigned int pub = (b == 0) ? (FLG_PFX | (unsigned int)c) : (FLG_AGG | (unsigned int)c);
        atomicExch(&status[b], pub);
    }
    __syncthreads();
    int total = s_tot;
    if (t == 0) {
        unsigned int run = 0;
        if (b > 0) {
            int i = b - 1;
            while (true) {
                unsigned int s = atomicAdd(&status[i], 0u);
                if (s & FLG_PFX) { run += s & FLG_VAL; break; }
                if (s & FLG_AGG) { run += s & FLG_VAL; --i; }
            }
            atomicExch(&status[b], FLG_PFX | (run + (unsigned int)total));
        }
        s_run = run;
    }
    __syncthreads();
    int gexcl = (int)s_run + wexcl[w] + (x - pair);
    if (idx < N_NODES) {
        row_start[idx] = gexcl;
        int run = gexcl;
        #pragma unroll
        for (int q = 0; q < 8; ++q) { start8[q * CPY + idx] = run; run += c0[q]; }
    }
    if (idx + 1 < N_NODES) {
        int g1 = gexcl + v0;
        row_start[idx + 1] = g1;
        int run = g1;
        #pragma unroll
        for (int q = 0; q < 8; ++q) { start8[q * CPY + idx + 1] = run; run += c1[q]; }
    }
    if (b == 0 && t == 0) row_start[N_NODES] = N_EDGES;
}

// ---------------- fill: atomic-free (positions precomputed in prep) ----------------

__global__ __launch_bounds__(256) void fill_kernel(const int* __restrict__ ei,
                                                   const int* __restrict__ pos_e,
                                                   const int* __restrict__ start8,
                                                   int* __restrict__ csr) {
    int b = blockIdx.x;   // 3125
    int e = b * 256 + threadIdx.x;
    int dst = ei[N_EDGES + e];
    csr[start8[(b & 7) * CPY + dst] + pos_e[e]] = ei[e];
}

// ---------------- mean aggregation: 16 lanes/row x 4 edges x 4-deep ILP (proven best) ------

#define ACC8(u)                                                                           \
    do {                                                                                  \
        a[0] += bf_lo((u).x); a[1] += bf_hi((u).x);                                        \
        a[2] += bf_lo((u).y); a[3] += bf_hi((u).y);                                        \
        a[4] += bf_lo((u).z); a[5] += bf_hi((u).z);                                        \
        a[6] += bf_lo((u).w); a[7] += bf_hi((u).w);                                        \
    } while (0)

__global__ __launch_bounds__(256) void agg_kernel(const unsigned short* __restrict__ xin,
                                                  const int* __restrict__ csr,
                                                  const int* __restrict__ row_start,
                                                  unsigned short* __restrict__ out) {
    int node = blockIdx.x * 4 + (threadIdx.x >> 6);
    int lane = threadIdx.x & 63;
    int g = lane >> 4, s16 = lane & 15;
    const uint4* base = (const uint4*)xin;   // one row = 16 uint4
    int cs = row_start[node], ce = row_start[node + 1];
    float a[8] = {0.f, 0.f, 0.f, 0.f, 0.f, 0.f, 0.f, 0.f};
    int i = cs;
    for (; i + 16 <= ce; i += 16) {
        int e0 = csr[i + g], e1 = csr[i + 4 + g], e2 = csr[i + 8 + g], e3 = csr[i + 12 + g];
        uint4 u0 = base[e0 * 16 + s16];
        uint4 u1 = base[e1 * 16 + s16];
        uint4 u2 = base[e2 * 16 + s16];
        uint4 u3 = base[e3 * 16 + s16];
        ACC8(u0); ACC8(u1); ACC8(u2); ACC8(u3);
    }
    if (i + 8 <= ce) {
        int e0 = csr[i + g], e1 = csr[i + 4 + g];
        uint4 u0 = base[e0 * 16 + s16];
        uint4 u1 = base[e1 * 16 + s16];
        ACC8(u0); ACC8(u1);
        i += 8;
    }
    if (i + 4 <= ce) {
        int e0 = csr[i + g];
        uint4 u0 = base[e0 * 16 + s16];
        ACC8(u0);
        i += 4;
    }
    if (i + g < ce) {
        int e0 = csr[i + g];
        uint4 u0 = base[e0 * 16 + s16];
        ACC8(u0);
    }
    #pragma unroll
    for (int k = 0; k < 8; ++k) {
        a[k] += __shfl_xor(a[k], 16);
        a[k] += __shfl_xor(a[k], 32);
    }
    if (g == 0) {
        int deg = ce - cs;
        float inv = 1.f / (float)(deg > 0 ? deg : 1);
        uint4 p;
        p.x = (unsigned int)f2bf(a[0] * inv) | ((unsigned int)f2bf(a[1] * inv) << 16);
        p.y = (unsigned int)f2bf(a[2] * inv) | ((unsigned int)f2bf(a[3] * inv) << 16);
        p.z = (unsigned int)f2bf(a[4] * inv) | ((unsigned int)f2bf(a[5] * inv) << 16);
        p.w = (unsigned int)f2bf(a[6] * inv) | ((unsigned int)f2bf(a[7] * inv) << 16);
        ((uint4*)out)[node * 16 + s16] = p;
    }
}

// ---------------- MFMA linear: C(bf16) = sum_p A_p @ W_p^T + bias [relu] ----------------
// ROWS=64 x 128-col block, 4 waves 2x2 (wave = 32 rows x 64 cols).
// Weights in fragment-major layout; only 2 k-steps of frags live in regs (wcur/wnxt).
// STATS: per-block column sum/sumsq -> partials (non-atomic, transposed layout).
// BNFUSE: A_{P-1} raw -> affine+PReLU on fragments; coefs from coef_in via LDS.

template <int P, int RELU, int STATS, int BNFUSE>
__global__ __launch_bounds__(256, 3) void mfma_linear(
    const unsigned short* __restrict__ A0, const unsigned short* __restrict__ A1,
    const unsigned short* __restrict__ A2,
    const unsigned short* __restrict__ W0, const unsigned short* __restrict__ W1,
    const unsigned short* __restrict__ W2,
    const float* __restrict__ bias, unsigned short* __restrict__ C,
    float* __restrict__ partials,
    const float* __restrict__ coef_in, const float* __restrict__ bn_a,
    int n_rows) {
    constexpr int ROWS = 64;
    constexpr int S = P * 16;          // 16B slots per LDS row
    constexpr int KS = P * 4;          // total k-steps of 32
    constexpr int MR = 2;              // m-frags per wave (32 rows)
    __shared__ char lds[ROWS * P * 256];
    __shared__ float csc[128], csf[128];
    int t = threadIdx.x;
    int lane = t & 63;
    int kq = lane >> 4;
    int wr = (t >> 7) & 1, wc = (t >> 6) & 1;
    int row_base = blockIdx.x * ROWS;

    // stage activations: LDS linear dest, swizzled global source
    #pragma unroll
    for (int c = 0; c < 4 * P; ++c) {
        int flat = c * 256 + t;
        int row = flat / S;
        int s = flat - row * S;
        int ss = s ^ (row & 7);
        int grow = row_base + row;
        if (grow >= n_rows) grow = n_rows - 1;
        const unsigned short* Ap;
        if (P == 2) Ap = (ss < 16) ? A0 : A1;
        else if (P == 3) Ap = (ss < 16) ? A0 : (ss < 32 ? A1 : A2);
        else Ap = A0;
        const unsigned short* srcp = Ap + (size_t)grow * 128 + (ss & 15) * 8;
        __builtin_amdgcn_global_load_lds((gptr_t)srcp, (sptr_t)(lds + flat * 16), 16, 0, 0);
    }

    float alpha = 0.f;
    if (BNFUSE) {
        if (t < 128) {
            csc[t] = coef_in[t];
            csf[t] = coef_in[128 + t];
        }
        alpha = bn_a[0];
    }

    // fragment-major weight base for this thread: slot = (ksp*4+kq)*128 + col
    int col0 = wc * 64 + (lane & 15);
    short8_t wcur[4], wnxt[4];
    {
        const unsigned short* base = W0 + ((size_t)(kq * 128 + col0)) * 8;
        #pragma unroll
        for (int nn = 0; nn < 4; ++nn) wcur[nn] = *(const short8_t*)(base + nn * 128);
    }

    f32x4 acc[MR][4];
    #pragma unroll
    for (int m = 0; m < MR; ++m)
        #pragma unroll
        for (int nn = 0; nn < 4; ++nn)
            acc[m][nn] = (f32x4){0.f, 0.f, 0.f, 0.f};

    __syncthreads();   // drains vmcnt (global_load_lds); csc/csf visible

    #pragma unroll
    for (int ksf = 0; ksf < KS; ++ksf) {
        // prefetch next k-step's weight fragments (coalesced 256B runs, L2-hot)
        if (ksf + 1 < KS) {
            const unsigned short* Wn = ((ksf + 1) < 4) ? W0 : (((ksf + 1) < 8) ? W1 : W2);
            int ksp1 = (ksf + 1) & 3;
            const unsigned short* base = Wn + ((size_t)((ksp1 * 4 + kq) * 128 + col0)) * 8;
            #pragma unroll
            for (int nn = 0; nn < 4; ++nn) wnxt[nn] = *(const short8_t*)(base + nn * 128);
        }
        short8_t a[MR];
        #pragma unroll
        for (int m = 0; m < MR; ++m) {
            int row = wr * 32 + m * 16 + (lane & 15);
            int s = ksf * 4 + kq;
            int off = row * (P * 256) + ((s ^ (row & 7)) * 16);
            a[m] = *(const short8_t*)(lds + off);
        }
        if (BNFUSE && ksf >= KS - 4) {
            int c0 = (ksf & 3) * 32 + kq * 8;   // local column in A_{P-1}
            #pragma unroll
            for (int m = 0; m < MR; ++m) {
                unsigned int* au = (unsigned int*)&a[m];
                #pragma unroll
                for (int u = 0; u < 4; ++u) {
                    int c = c0 + u * 2;
                    float lo = bf_lo(au[u]) * csc[c] + csf[c];
                    float hi = bf_hi(au[u]) * csc[c + 1] + csf[c + 1];
                    lo = lo >= 0.f ? lo : alpha * lo;
                    hi = hi >= 0.f ? hi : alpha * hi;
                    au[u] = (unsigned int)f2bf(lo) | ((unsigned int)f2bf(hi) << 16);
                }
            }
        }
        #pragma unroll
        for (int m = 0; m < MR; ++m)
            #pragma unroll
            for (int nn = 0; nn < 4; ++nn)
                acc[m][nn] = __builtin_amdgcn_mfma_f32_16x16x32_bf16(a[m], wcur[nn], acc[m][nn], 0, 0, 0);
        if (ksf + 1 < KS) {
            #pragma unroll
            for (int nn = 0; nn < 4; ++nn) wcur[nn] = wnxt[nn];
        }
    }

    // epilogue: bias [+relu], bf16 store (+ per-block BN partial stats, non-atomic)
    #pragma unroll
    for (int nn = 0; nn < 4; ++nn) {
        int col = wc * 64 + nn * 16 + (lane & 15);
        float badd = bias[col];
        float ps = 0.f, pq = 0.f;
        #pragma unroll
        for (int m = 0; m < MR; ++m) {
            #pragma unroll
            for (int j = 0; j < 4; ++j) {
                int row = row_base + wr * 32 + m * 16 + kq * 4 + j;
                if (row < n_rows) {
                    float v = acc[m][nn][j] + badd;
                    if (RELU) v = fmaxf(v, 0.f);
                    C[(size_t)row * 128 + col] = f2bf(v);
                    if (STATS) { ps += v; pq += v * v; }
                }
            }
        }
        if (STATS) {
            ps += __shfl_xor(ps, 16); ps += __shfl_xor(ps, 32);
            pq += __shfl_xor(pq, 16); pq += __shfl_xor(pq, 32);
            if (lane < 16) {
                int part = blockIdx.x * 2 + wr;
                partials[col * 2 * NPART_PAD + part] = ps;
                partials[col * 2 * NPART_PAD + NPART_PAD + part] = pq;
            }
        }
    }
}

// ---------------- BN: reduce partials -> coefs (one block per column) ----------------

__global__ __launch_bounds__(256) void bn_reduce_kernel(const float* __restrict__ partials,
                                                        const float* __restrict__ g,
                                                        const float* __restrict__ b,
                                                        float* __restrict__ coef,
                                                        int npart, float invn) {
    int c = blockIdx.x;   // 128 blocks, one column each
    int t = threadIdx.x;
    const float* ps = partials + (size_t)c * 2 * NPART_PAD;
    float s = 0.f, q = 0.f;
    for (int r = t; r < npart; r += 256) {
        s += ps[r];
        q += ps[NPART_PAD + r];
    }
    #pragma unroll
    for (int off = 1; off < 64; off <<= 1) {
        s += __shfl_xor(s, off);
        q += __shfl_xor(q, off);
    }
    __shared__ float sh[8];
    int w = t >> 6;
    if ((t & 63) == 0) { sh[w] = s; sh[4 + w] = q; }
    __syncthreads();
    if (t == 0) {
        float S = sh[0] + sh[1] + sh[2] + sh[3];
        float Q = sh[4] + sh[5] + sh[6] + sh[7];
        float m = S * invn;
        float var = Q * invn - m * m;
        float sc = g[c] * rsqrtf(var + BN_EPS);
        coef[c] = sc;
        coef[128 + c] = b[c] - m * sc;
    }
}

// ---------------- BN apply: bf16 Y in, bf16 X out (coefs precomputed) ----------------

__global__ void bn_apply_kernel(const uint4* __restrict__ y4, const float* __restrict__ coef,
                                const float* __restrict__ a, uint4* __restrict__ xout, int n) {
    int idx = blockIdx.x * blockDim.x + threadIdx.x;
    int total = n * 16;   // uint4 per row = 16 (8 bf16 each)
    float alpha = a[0];
    const float4* c4 = (const float4*)coef;
    for (; idx < total; idx += gridDim.x * blockDim.x) {
        int d = idx & 15;
        uint4 v = y4[idx];
        float4 sc0 = c4[d * 2], sc1 = c4[d * 2 + 1];
        float4 sf0 = c4[32 + d * 2], sf1 = c4[32 + d * 2 + 1];
        float r0 = bf_lo(v.x) * sc0.x + sf0.x;
        float r1 = bf_hi(v.x) * sc0.y + sf0.y;
        float r2 = bf_lo(v.y) * sc0.z + sf0.z;
        float r3 = bf_hi(v.y) * sc0.w + sf0.w;
        float r4 = bf_lo(v.z) * sc1.x + sf1.x;
        float r5 = bf_hi(v.z) * sc1.y + sf1.y;
        float r6 = bf_lo(v.w) * sc1.z + sf1.z;
        float r7 = bf_hi(v.w) * sc1.w + sf1.w;
        r0 = r0 >= 0.f ? r0 : alpha * r0;
        r1 = r1 >= 0.f ? r1 : alpha * r1;
        r2 = r2 >= 0.f ? r2 : alpha * r2;
        r3 = r3 >= 0.f ? r3 : alpha * r3;
        r4 = r4 >= 0.f ? r4 : alpha * r4;
        r5 = r5 >= 0.f ? r5 : alpha * r5;
        r6 = r6 >= 0.f ? r6 : alpha * r6;
        r7 = r7 >= 0.f ? r7 : alpha * r7;
        uint4 o;
        o.x = (unsigned int)f2bf(r0) | ((unsigned int)f2bf(r1) << 16);
        o.y = (unsigned int)f2bf(r2) | ((unsigned int)f2bf(r3) << 16);
        o.z = (unsigned int)f2bf(r4) | ((unsigned int)f2bf(r5) << 16);
        o.w = (unsigned int)f2bf(r6) | ((unsigned int)f2bf(r7) << 16);
        xout[idx] = o;
    }
}

// ---------------- pooling + classifier ----------------

__global__ void pool_kernel(const unsigned short* __restrict__ h, const int* __restrict__ g_start,
                            float* __restrict__ pooled) {
    int g = blockIdx.x >> 3, part = blockIdx.x & 7;
    int d = threadIdx.x;  // 128
    int s = g_start[g], e = g_start[g + 1];
    int len = e - s;
    int ps = s + ((len * part) >> 3), pe = s + ((len * (part + 1)) >> 3);
    float acc = 0.f;
    for (int i = ps; i < pe; ++i) {
        unsigned short v = h[(size_t)i * DIM + d];
        acc += __uint_as_float(((unsigned int)v) << 16);
    }
    atomicAdd(&pooled[g * DIM + d], acc);
}

__global__ void final_kernel(const float* __restrict__ pooled, const int* __restrict__ g_start,
                             const float* __restrict__ Wf, const float* __restrict__ bf,
                             float* __restrict__ out) {
    int idx = blockIdx.x * 256 + threadIdx.x;  // 2048 = 64 groups x 32 classes
    int g = idx >> 5, c = idx & 31;
    int cnt = g_start[g + 1] - g_start[g];
    float inv = 1.f / (float)(cnt > 0 ? cnt : 1);
    float acc = 0.f;
    for (int dd = 0; dd < 128; ++dd) acc += pooled[g * DIM + dd] * Wf[c * DIM + dd];
    out[idx] = acc * inv + bf[c];
}

// ---------------- launcher ----------------

extern "C" void kernel_launch(void* const* d_in, const int* in_sizes, int n_in,
                              void* d_out, int out_size, void* d_ws, size_t ws_size,
                              hipStream_t stream) {
    const float* x = (const float*)d_in[0];
    const int* ei = (const int*)d_in[1];
    const int* batch = (const int*)d_in[2];
    const float* Wl[3] = {(const float*)d_in[3], (const float*)d_in[9], (const float*)d_in[15]};
    const float* bl[3] = {(const float*)d_in[4], (const float*)d_in[10], (const float*)d_in[16]};
    const float* Wr[3] = {(const float*)d_in[5], (const float*)d_in[11], (const float*)d_in[17]};
    const float* gg[3] = {(const float*)d_in[6], (const float*)d_in[12], (const float*)d_in[18]};
    const float* bb[3] = {(const float*)d_in[7], (const float*)d_in[13], (const float*)d_in[19]};
    const float* aa[3] = {(const float*)d_in[8], (const float*)d_in[14], (const float*)d_in[20]};
    const float* Wjk = (const float*)d_in[21];
    const float* bjk = (const float*)d_in[22];
    const float* Wf = (const float*)d_in[23];
    const float* bf = (const float*)d_in[24];
    float* out = (float*)d_out;

    char* ws = (char*)d_ws;
    size_t off = 0;
    auto alloc = [&](size_t bytes) {
        void* p = ws + off;
        off += (bytes + 255) & ~(size_t)255;
        return p;
    };
    // ---- contiguous zero region: cnt8 | scan_status | pooled ----
    size_t zero_begin = off;
    int* cnt8 = (int*)alloc((size_t)8 * CPY * 4);
    unsigned int* scan_status = (unsigned int*)alloc(SCAN_BLOCKS * 4);
    float* pooled = (float*)alloc(NGROUPS * DIM * 4);
    size_t zero_bytes = off - zero_begin;
    // ---- rest ----
    int* pos_e = (int*)alloc((size_t)N_EDGES * 4);
    int* row_start = (int*)alloc((N_NODES + 1) * 4);
    int* start8 = (int*)alloc((size_t)8 * CPY * 4);
    int* csr = (int*)alloc((size_t)N_EDGES * 4);
    int* g_start = (int*)alloc((NGROUPS + 1) * 4);
    float* bn_part = (float*)alloc((size_t)128 * 2 * NPART_PAD * 4);
    float* bn_coef = (float*)alloc(256 * 4);
    unsigned short* Y = (unsigned short*)alloc((size_t)N_NODES * DIM * 2);
    unsigned short* X0 = (unsigned short*)alloc((size_t)N_NODES * DIM * 2);
    unsigned short* X1 = (unsigned short*)alloc((size_t)N_NODES * DIM * 2);
    unsigned short* X2 = (unsigned short*)alloc((size_t)N_NODES * DIM * 2);
    unsigned short* AGGb = (unsigned short*)alloc((size_t)N_NODES * DIM * 2);
    unsigned short* Wb = (unsigned short*)alloc((size_t)9 * 16384 * 2);
    unsigned short* Wlb[3] = {Wb, Wb + 2 * 16384, Wb + 4 * 16384};
    unsigned short* Wrb[3] = {Wb + 16384, Wb + 3 * 16384, Wb + 5 * 16384};
    unsigned short* Wjkb = Wb + 6 * 16384;
    unsigned short* Xl[2] = {X1, X2};

    hipMemsetAsync(ws + zero_begin, 0, zero_bytes, stream);

    prep_kernel<<<PREP_TOTAL, 256, 0, stream>>>(ei, cnt8, pos_e, batch, g_start, x,
                                                (unsigned int*)X0,
                                                Wl[0], Wr[0], Wl[1], Wr[1], Wl[2], Wr[2], Wb,
                                                Wjk, Wjkb);
    scan_kernel<<<SCAN_BLOCKS, 256, 0, stream>>>(cnt8, row_start, start8, scan_status);
    fill_kernel<<<PREP_COUNT, 256, 0, stream>>>(ei, pos_e, start8, csr);

    const int NBLK64 = (N_NODES + 63) / 64;   // 782
    const unsigned short* xin = X0;
    for (int l = 0; l < 3; ++l) {
        agg_kernel<<<N_NODES / 4, 256, 0, stream>>>(xin, csr, row_start, AGGb);
        mfma_linear<2, 0, 1, 0><<<NBLK64, 256, 0, stream>>>(
            AGGb, xin, nullptr, Wlb[l], Wrb[l], nullptr, bl[l], Y, bn_part,
            nullptr, nullptr, N_NODES);
        bn_reduce_kernel<<<128, 256, 0, stream>>>(bn_part, gg[l], bb[l], bn_coef, 2 * NBLK64, 1.f / N_NODES);
        if (l < 2) {
            bn_apply_kernel<<<2048, 256, 0, stream>>>(
                (const uint4*)Y, bn_coef, aa[l], (uint4*)Xl[l], N_NODES);
            xin = Xl[l];
        }
    }

    // JK: Y = relu(X1@Wjk0^T + X2@Wjk1^T + BN3(Y)@Wjk2^T + bjk) — BN3+PReLU fused on A2,
    // coefs precomputed by layer-3 bn_reduce.
    mfma_linear<3, 1, 0, 1><<<NBLK64, 256, 0, stream>>>(
        X1, X2, Y, Wjkb, Wjkb + 16384, Wjkb + 2 * 16384, bjk, Y, nullptr,
        bn_coef, aa[2], N_NODES);

    pool_kernel<<<NGROUPS * 8, 128, 0, stream>>>(Y, g_start, pooled);
    final_kernel<<<8, 256, 0, stream>>>(pooled, g_start, Wf, bf, out);
}